// Round 1
// baseline (1069.550 us; speedup 1.0000x reference)
//
#include <hip/hip_runtime.h>

// ---------------------------------------------------------------------------
// GCN 3-layer forward on MI355X.
// Pipeline: build deg -> dinv -> CSR(by dst) once; then per layer:
//   T = H @ W  (fp32 tiled GEMM, W in LDS)
//   H' = relu( segsum_{dst}( T[src] * dinv[src]*dinv[dst] ) + b )
// ---------------------------------------------------------------------------

__global__ void k_init_deg(int* __restrict__ deg, int n) {
    int i = blockIdx.x * blockDim.x + threadIdx.x;
    if (i < n) deg[i] = 1;  // self-loop contributes 1
}

__global__ void k_hist(const int* __restrict__ dst, int* __restrict__ deg, int E) {
    int e = blockIdx.x * blockDim.x + threadIdx.x;
    if (e < E) atomicAdd(&deg[dst[e]], 1);
}

// per-block (1024 elems) local exclusive scan; block totals to bsum
__global__ __launch_bounds__(256) void k_scan1(const int* __restrict__ deg,
                                               int* __restrict__ loc,
                                               int* __restrict__ bsum, int n) {
    __shared__ int sh[256];
    int tid = threadIdx.x;
    int base = blockIdx.x * 1024 + tid * 4;
    int v[4];
#pragma unroll
    for (int j = 0; j < 4; j++) v[j] = (base + j < n) ? deg[base + j] : 0;
    int tsum = v[0] + v[1] + v[2] + v[3];
    int val = tsum;
    sh[tid] = val;
    __syncthreads();
    for (int off = 1; off < 256; off <<= 1) {
        int o = (tid >= off) ? sh[tid - off] : 0;
        __syncthreads();
        val += o;
        sh[tid] = val;
        __syncthreads();
    }
    if (tid == 255) bsum[blockIdx.x] = val;
    int run = val - tsum;  // exclusive over thread sums
#pragma unroll
    for (int j = 0; j < 4; j++) {
        if (base + j < n) loc[base + j] = run;
        run += v[j];
    }
}

// single block: exclusive scan of nb block sums (nb <= 256)
__global__ __launch_bounds__(256) void k_scan2(int* __restrict__ bsum, int nb) {
    __shared__ int sh[256];
    int tid = threadIdx.x;
    int orig = (tid < nb) ? bsum[tid] : 0;
    int val = orig;
    sh[tid] = val;
    __syncthreads();
    for (int off = 1; off < 256; off <<= 1) {
        int o = (tid >= off) ? sh[tid - off] : 0;
        __syncthreads();
        val += o;
        sh[tid] = val;
        __syncthreads();
    }
    if (tid < nb) bsum[tid] = val - orig;      // exclusive
    if (tid == nb - 1) bsum[nb] = val;         // total = E + N
}

__global__ void k_scan3(const int* __restrict__ deg, int* __restrict__ offs,
                        const int* __restrict__ bsum, int* __restrict__ cursor,
                        float* __restrict__ dinv, int n, int nb) {
    int i = blockIdx.x * blockDim.x + threadIdx.x;
    if (i < n) {
        int off = offs[i] + bsum[i >> 10];
        offs[i] = off;
        cursor[i] = off;
        dinv[i] = rsqrtf((float)deg[i]);
    }
    if (i == 0) offs[n] = bsum[nb];
}

__global__ void k_fill(const int* __restrict__ esrc, const int* __restrict__ edst,
                       const float* __restrict__ dinv, int* __restrict__ cursor,
                       int* __restrict__ csrc, float* __restrict__ cw, int E, int n) {
    int e = blockIdx.x * blockDim.x + threadIdx.x;
    if (e < E) {
        int s = esrc[e], d = edst[e];
        int pos = atomicAdd(&cursor[d], 1);
        csrc[pos] = s;
        cw[pos] = dinv[s] * dinv[d];
    } else if (e < E + n) {
        int i = e - E;
        int pos = atomicAdd(&cursor[i], 1);
        csrc[pos] = i;
        float di = dinv[i];
        cw[pos] = di * di;
    }
}

// T[N,F] = H[N,128] @ W[128,F], W staged in LDS, 64 rows/block, float4 cols
template <int F>
__global__ __launch_bounds__(256) void k_gemm(const float* __restrict__ H,
                                              const float* __restrict__ W,
                                              float* __restrict__ T, int n) {
    constexpr int TX = F / 4;        // 32 (F=128) or 16 (F=64)
    constexpr int TY = 256 / TX;     // 8 or 16
    constexpr int RPT = 64 / TY;     // 8 or 4
    __shared__ float Wl[128 * F];
    int tid = threadIdx.x;
    for (int i = tid * 4; i < 128 * F; i += 1024)
        *(float4*)&Wl[i] = *(const float4*)&W[i];
    __syncthreads();
    int tx = tid % TX, ty = tid / TX;
    int row0 = blockIdx.x * 64 + ty * RPT;
    float4 acc[RPT];
#pragma unroll
    for (int i = 0; i < RPT; i++) acc[i] = float4{0.f, 0.f, 0.f, 0.f};
    for (int k4 = 0; k4 < 32; k4++) {
        float4 xq[RPT];
#pragma unroll
        for (int i = 0; i < RPT; i++) {
            int r = row0 + i;
            xq[i] = (r < n) ? *(const float4*)&H[r * 128 + k4 * 4]
                            : float4{0.f, 0.f, 0.f, 0.f};
        }
#pragma unroll
        for (int kk = 0; kk < 4; kk++) {
            float4 wv = *(const float4*)&Wl[(k4 * 4 + kk) * F + tx * 4];
#pragma unroll
            for (int i = 0; i < RPT; i++) {
                float xs = (&xq[i].x)[kk];
                acc[i].x += xs * wv.x;
                acc[i].y += xs * wv.y;
                acc[i].z += xs * wv.z;
                acc[i].w += xs * wv.w;
            }
        }
    }
#pragma unroll
    for (int i = 0; i < RPT; i++) {
        int r = row0 + i;
        if (r < n) *(float4*)&T[r * F + tx * 4] = acc[i];
    }
}

// one wave per dst node; lanes own features; edges broadcast via shfl
template <int F, bool RELU>
__global__ __launch_bounds__(256) void k_prop(const float* __restrict__ T,
                                              const int* __restrict__ offs,
                                              const int* __restrict__ csrc,
                                              const float* __restrict__ cw,
                                              const float* __restrict__ bias,
                                              float* __restrict__ Out, int n) {
    int wid = (blockIdx.x * blockDim.x + threadIdx.x) >> 6;  // node id
    int lane = threadIdx.x & 63;
    if (wid >= n) return;
    int beg = offs[wid], end = offs[wid + 1];
    float accx = 0.f, accy = 0.f;
    for (int base = beg; base < end; base += 64) {
        int cnt = min(64, end - base);
        int sv = (lane < cnt) ? csrc[base + lane] : 0;
        float wv = (lane < cnt) ? cw[base + lane] : 0.f;
        for (int j = 0; j < cnt; j++) {
            int s = __shfl(sv, j);
            float w = __shfl(wv, j);
            if constexpr (F == 128) {
                float2 v = *(const float2*)&T[s * 128 + lane * 2];
                accx += w * v.x;
                accy += w * v.y;
            } else {
                accx += w * T[s * 64 + lane];
            }
        }
    }
    if constexpr (F == 128) {
        float2 b = *(const float2*)&bias[lane * 2];
        accx += b.x;
        accy += b.y;
        if (RELU) { accx = fmaxf(accx, 0.f); accy = fmaxf(accy, 0.f); }
        *(float2*)&Out[wid * 128 + lane * 2] = float2{accx, accy};
    } else {
        accx += bias[lane];
        if (RELU) accx = fmaxf(accx, 0.f);
        Out[wid * 64 + lane] = accx;
    }
}

extern "C" void kernel_launch(void* const* d_in, const int* in_sizes, int n_in,
                              void* d_out, int out_size, void* d_ws, size_t ws_size,
                              hipStream_t stream) {
    const float* x  = (const float*)d_in[0];
    const int*   ei = (const int*)d_in[1];
    const float* W1 = (const float*)d_in[2];
    const float* b1 = (const float*)d_in[3];
    const float* W2 = (const float*)d_in[4];
    const float* b2 = (const float*)d_in[5];
    const float* W3 = (const float*)d_in[6];
    const float* b3 = (const float*)d_in[7];
    float* out = (float*)d_out;

    const int HID = in_sizes[3];            // 128
    const int IN  = in_sizes[2] / HID;      // 128
    const int N   = in_sizes[0] / IN;       // 100000
    const int E   = in_sizes[1] / 2;        // 1600000
    const int nb  = (N + 1023) / 1024;      // scan blocks

    const int* esrc = ei;
    const int* edst = ei + E;

    // workspace carve-up (256B aligned)
    char* p = (char*)d_ws;
    auto alloc = [&](size_t bytes) {
        void* r = (void*)p;
        p += (bytes + 255) & ~(size_t)255;
        return r;
    };
    int*   deg    = (int*)alloc((size_t)N * 4);
    float* dinv   = (float*)alloc((size_t)N * 4);
    int*   offs   = (int*)alloc((size_t)(N + 1) * 4);
    int*   bsum   = (int*)alloc((size_t)(nb + 2) * 4);
    int*   cursor = (int*)alloc((size_t)N * 4);
    int*   csrc   = (int*)alloc((size_t)(E + N) * 4);
    float* cwt    = (float*)alloc((size_t)(E + N) * 4);
    float* t0     = (float*)alloc((size_t)N * 128 * 4);
    float* h0     = (float*)alloc((size_t)N * 128 * 4);
    (void)ws_size; (void)n_in; (void)out_size;

    const int B = 256;
    // --- graph norm + CSR build (once; reused by all 3 layers) ---
    k_init_deg<<<(N + B - 1) / B, B, 0, stream>>>(deg, N);
    k_hist<<<(E + B - 1) / B, B, 0, stream>>>(edst, deg, E);
    k_scan1<<<nb, B, 0, stream>>>(deg, offs, bsum, N);
    k_scan2<<<1, B, 0, stream>>>(bsum, nb);
    k_scan3<<<(N + B - 1) / B, B, 0, stream>>>(deg, offs, bsum, cursor, dinv, N, nb);
    k_fill<<<(E + N + B - 1) / B, B, 0, stream>>>(esrc, edst, dinv, cursor, csrc, cwt, E, N);

    // --- layer 1 ---
    k_gemm<128><<<(N + 63) / 64, B, 0, stream>>>(x, W1, t0, N);
    k_prop<128, true><<<(N * 64 + B - 1) / B, B, 0, stream>>>(t0, offs, csrc, cwt, b1, h0, N);
    // --- layer 2 ---
    k_gemm<128><<<(N + 63) / 64, B, 0, stream>>>(h0, W2, t0, N);
    k_prop<128, true><<<(N * 64 + B - 1) / B, B, 0, stream>>>(t0, offs, csrc, cwt, b2, h0, N);
    // --- layer 3 (OUT=64, no relu, into d_out) ---
    k_gemm<64><<<(N + 63) / 64, B, 0, stream>>>(h0, W3, t0, N);
    k_prop<64, false><<<(N * 64 + B - 1) / B, B, 0, stream>>>(t0, offs, csrc, cwt, b3, out, N);
}

// Round 2
// 824.699 us; speedup vs baseline: 1.2969x; 1.2969x over previous
//
#include <hip/hip_runtime.h>

// ---------------------------------------------------------------------------
// GCN 3-layer forward on MI355X.
// Pipeline: build deg -> dinv -> CSR(by dst) once; then per layer:
//   T = H @ W  (fp32 tiled GEMM, W in LDS)
//   H' = relu( segsum_{dst}( T[src] * dinv[src]*dinv[dst] ) + b )
// R1: GEMM reworked for occupancy — 1024-thr blocks, 128 rows/block, RPT=4,
//     launch_bounds(1024,8) so 2 blocks/CU (128KB LDS) = 32 waves/CU.
// ---------------------------------------------------------------------------

__global__ void k_init_deg(int* __restrict__ deg, int n) {
    int i = blockIdx.x * blockDim.x + threadIdx.x;
    if (i < n) deg[i] = 1;  // self-loop contributes 1
}

__global__ void k_hist(const int* __restrict__ dst, int* __restrict__ deg, int E) {
    int e = blockIdx.x * blockDim.x + threadIdx.x;
    if (e < E) atomicAdd(&deg[dst[e]], 1);
}

// per-block (1024 elems) local exclusive scan; block totals to bsum
__global__ __launch_bounds__(256) void k_scan1(const int* __restrict__ deg,
                                               int* __restrict__ loc,
                                               int* __restrict__ bsum, int n) {
    __shared__ int sh[256];
    int tid = threadIdx.x;
    int base = blockIdx.x * 1024 + tid * 4;
    int v[4];
#pragma unroll
    for (int j = 0; j < 4; j++) v[j] = (base + j < n) ? deg[base + j] : 0;
    int tsum = v[0] + v[1] + v[2] + v[3];
    int val = tsum;
    sh[tid] = val;
    __syncthreads();
    for (int off = 1; off < 256; off <<= 1) {
        int o = (tid >= off) ? sh[tid - off] : 0;
        __syncthreads();
        val += o;
        sh[tid] = val;
        __syncthreads();
    }
    if (tid == 255) bsum[blockIdx.x] = val;
    int run = val - tsum;  // exclusive over thread sums
#pragma unroll
    for (int j = 0; j < 4; j++) {
        if (base + j < n) loc[base + j] = run;
        run += v[j];
    }
}

// single block: exclusive scan of nb block sums (nb <= 256)
__global__ __launch_bounds__(256) void k_scan2(int* __restrict__ bsum, int nb) {
    __shared__ int sh[256];
    int tid = threadIdx.x;
    int orig = (tid < nb) ? bsum[tid] : 0;
    int val = orig;
    sh[tid] = val;
    __syncthreads();
    for (int off = 1; off < 256; off <<= 1) {
        int o = (tid >= off) ? sh[tid - off] : 0;
        __syncthreads();
        val += o;
        sh[tid] = val;
        __syncthreads();
    }
    if (tid < nb) bsum[tid] = val - orig;      // exclusive
    if (tid == nb - 1) bsum[nb] = val;         // total = E + N
}

__global__ void k_scan3(const int* __restrict__ deg, int* __restrict__ offs,
                        const int* __restrict__ bsum, int* __restrict__ cursor,
                        float* __restrict__ dinv, int n, int nb) {
    int i = blockIdx.x * blockDim.x + threadIdx.x;
    if (i < n) {
        int off = offs[i] + bsum[i >> 10];
        offs[i] = off;
        cursor[i] = off;
        dinv[i] = rsqrtf((float)deg[i]);
    }
    if (i == 0) offs[n] = bsum[nb];
}

__global__ void k_fill(const int* __restrict__ esrc, const int* __restrict__ edst,
                       const float* __restrict__ dinv, int* __restrict__ cursor,
                       int* __restrict__ csrc, float* __restrict__ cw, int E, int n) {
    int e = blockIdx.x * blockDim.x + threadIdx.x;
    if (e < E) {
        int s = esrc[e], d = edst[e];
        int pos = atomicAdd(&cursor[d], 1);
        csrc[pos] = s;
        cw[pos] = dinv[s] * dinv[d];
    } else if (e < E + n) {
        int i = e - E;
        int pos = atomicAdd(&cursor[i], 1);
        csrc[pos] = i;
        float di = dinv[i];
        cw[pos] = di * di;
    }
}

// T[N,F] = H[N,128] @ W[128,F]. W staged in LDS (F*512 B), 128 rows/block,
// 1024 threads, each thread: RPT rows x 1 float4 col. 2 blocks/CU target.
template <int F>
__global__ __launch_bounds__(1024, 8) void k_gemm(const float* __restrict__ H,
                                                  const float* __restrict__ W,
                                                  float* __restrict__ T, int n) {
    constexpr int TX = F / 4;          // 32 (F=128) or 16 (F=64)
    constexpr int TY = 1024 / TX;      // 32 or 64
    constexpr int RPT = 128 / TY;      // 4 or 2
    __shared__ float Wl[128 * F];
    int tid = threadIdx.x;
#pragma unroll
    for (int i = 0; i < (128 * F) / 4096; i++)
        *(float4*)&Wl[tid * 4 + i * 4096] = *(const float4*)&W[tid * 4 + i * 4096];
    __syncthreads();
    int tx = tid % TX, ty = tid / TX;
    int row0 = blockIdx.x * 128 + ty * RPT;
    // clamp OOB rows (values unused; stores are guarded) -> unconditional loads
    const float* hp[RPT];
#pragma unroll
    for (int i = 0; i < RPT; i++) hp[i] = H + (size_t)min(row0 + i, n - 1) * 128;
    float4 acc[RPT];
#pragma unroll
    for (int i = 0; i < RPT; i++) acc[i] = float4{0.f, 0.f, 0.f, 0.f};
#pragma unroll 2
    for (int k4 = 0; k4 < 32; k4++) {
        float4 xq[RPT];
#pragma unroll
        for (int i = 0; i < RPT; i++) xq[i] = *(const float4*)(hp[i] + k4 * 4);
#pragma unroll
        for (int kk = 0; kk < 4; kk++) {
            float4 wv = *(const float4*)&Wl[(k4 * 4 + kk) * F + tx * 4];
#pragma unroll
            for (int i = 0; i < RPT; i++) {
                float xs = (&xq[i].x)[kk];
                acc[i].x += xs * wv.x;
                acc[i].y += xs * wv.y;
                acc[i].z += xs * wv.z;
                acc[i].w += xs * wv.w;
            }
        }
    }
#pragma unroll
    for (int i = 0; i < RPT; i++) {
        int r = row0 + i;
        if (r < n) *(float4*)&T[(size_t)r * F + tx * 4] = acc[i];
    }
}

// one wave per dst node; lanes own features; edges broadcast via shfl
template <int F, bool RELU>
__global__ __launch_bounds__(256) void k_prop(const float* __restrict__ T,
                                              const int* __restrict__ offs,
                                              const int* __restrict__ csrc,
                                              const float* __restrict__ cw,
                                              const float* __restrict__ bias,
                                              float* __restrict__ Out, int n) {
    int wid = (blockIdx.x * blockDim.x + threadIdx.x) >> 6;  // node id
    int lane = threadIdx.x & 63;
    if (wid >= n) return;
    int beg = offs[wid], end = offs[wid + 1];
    float accx = 0.f, accy = 0.f;
    for (int base = beg; base < end; base += 64) {
        int cnt = min(64, end - base);
        int sv = (lane < cnt) ? csrc[base + lane] : 0;
        float wv = (lane < cnt) ? cw[base + lane] : 0.f;
        for (int j = 0; j < cnt; j++) {
            int s = __shfl(sv, j);
            float w = __shfl(wv, j);
            if constexpr (F == 128) {
                float2 v = *(const float2*)&T[(size_t)s * 128 + lane * 2];
                accx += w * v.x;
                accy += w * v.y;
            } else {
                accx += w * T[(size_t)s * 64 + lane];
            }
        }
    }
    if constexpr (F == 128) {
        float2 b = *(const float2*)&bias[lane * 2];
        accx += b.x;
        accy += b.y;
        if (RELU) { accx = fmaxf(accx, 0.f); accy = fmaxf(accy, 0.f); }
        *(float2*)&Out[(size_t)wid * 128 + lane * 2] = float2{accx, accy};
    } else {
        accx += bias[lane];
        if (RELU) accx = fmaxf(accx, 0.f);
        Out[(size_t)wid * 64 + lane] = accx;
    }
}

extern "C" void kernel_launch(void* const* d_in, const int* in_sizes, int n_in,
                              void* d_out, int out_size, void* d_ws, size_t ws_size,
                              hipStream_t stream) {
    const float* x  = (const float*)d_in[0];
    const int*   ei = (const int*)d_in[1];
    const float* W1 = (const float*)d_in[2];
    const float* b1 = (const float*)d_in[3];
    const float* W2 = (const float*)d_in[4];
    const float* b2 = (const float*)d_in[5];
    const float* W3 = (const float*)d_in[6];
    const float* b3 = (const float*)d_in[7];
    float* out = (float*)d_out;

    const int HID = in_sizes[3];            // 128
    const int IN  = in_sizes[2] / HID;      // 128
    const int N   = in_sizes[0] / IN;       // 100000
    const int E   = in_sizes[1] / 2;        // 1600000
    const int nb  = (N + 1023) / 1024;      // scan blocks

    const int* esrc = ei;
    const int* edst = ei + E;

    // workspace carve-up (256B aligned)
    char* p = (char*)d_ws;
    auto alloc = [&](size_t bytes) {
        void* r = (void*)p;
        p += (bytes + 255) & ~(size_t)255;
        return r;
    };
    int*   deg    = (int*)alloc((size_t)N * 4);
    float* dinv   = (float*)alloc((size_t)N * 4);
    int*   offs   = (int*)alloc((size_t)(N + 1) * 4);
    int*   bsum   = (int*)alloc((size_t)(nb + 2) * 4);
    int*   cursor = (int*)alloc((size_t)N * 4);
    int*   csrc   = (int*)alloc((size_t)(E + N) * 4);
    float* cwt    = (float*)alloc((size_t)(E + N) * 4);
    float* t0     = (float*)alloc((size_t)N * 128 * 4);
    float* h0     = (float*)alloc((size_t)N * 128 * 4);
    (void)ws_size; (void)n_in; (void)out_size;

    const int B = 256;
    // --- graph norm + CSR build (once; reused by all 3 layers) ---
    k_init_deg<<<(N + B - 1) / B, B, 0, stream>>>(deg, N);
    k_hist<<<(E + B - 1) / B, B, 0, stream>>>(edst, deg, E);
    k_scan1<<<nb, B, 0, stream>>>(deg, offs, bsum, N);
    k_scan2<<<1, B, 0, stream>>>(bsum, nb);
    k_scan3<<<(N + B - 1) / B, B, 0, stream>>>(deg, offs, bsum, cursor, dinv, N, nb);
    k_fill<<<(E + N + B - 1) / B, B, 0, stream>>>(esrc, edst, dinv, cursor, csrc, cwt, E, N);

    const int gb = (N + 127) / 128;  // gemm row-blocks
    // --- layer 1 ---
    k_gemm<128><<<gb, 1024, 0, stream>>>(x, W1, t0, N);
    k_prop<128, true><<<(N * 64 + B - 1) / B, B, 0, stream>>>(t0, offs, csrc, cwt, b1, h0, N);
    // --- layer 2 ---
    k_gemm<128><<<gb, 1024, 0, stream>>>(h0, W2, t0, N);
    k_prop<128, true><<<(N * 64 + B - 1) / B, B, 0, stream>>>(t0, offs, csrc, cwt, b2, h0, N);
    // --- layer 3 (OUT=64, no relu, into d_out) ---
    k_gemm<64><<<gb, 1024, 0, stream>>>(h0, W3, t0, N);
    k_prop<64, false><<<(N * 64 + B - 1) / B, B, 0, stream>>>(t0, offs, csrc, cwt, b3, out, N);
}

// Round 3
// 746.515 us; speedup vs baseline: 1.4327x; 1.1047x over previous
//
#include <hip/hip_runtime.h>

// ---------------------------------------------------------------------------
// GCN 3-layer forward on MI355X.
// Pipeline: build deg -> dinv -> CSR(by dst, packed {src,w}) once; per layer:
//   T = H @ W  (fp32 tiled GEMM, W in LDS)
//   H' = relu( segsum_{dst}( T[src] * w_e ) + b )
// R1: GEMM 1024-thr blocks, 128 rows/block, 2 blocks/CU (128KB LDS).
// R2: prop rewritten — float4 row gathers (512B per half-wave), 2 edges/step
//     (4 for F=64), packed int2 edge records, fp64 accumulators (order-safe).
// ---------------------------------------------------------------------------

__global__ void k_init_deg(int* __restrict__ deg, int n) {
    int i = blockIdx.x * blockDim.x + threadIdx.x;
    if (i < n) deg[i] = 1;  // self-loop contributes 1
}

__global__ void k_hist(const int* __restrict__ dst, int* __restrict__ deg, int E) {
    int e = blockIdx.x * blockDim.x + threadIdx.x;
    if (e < E) atomicAdd(&deg[dst[e]], 1);
}

// per-block (1024 elems) local exclusive scan; block totals to bsum
__global__ __launch_bounds__(256) void k_scan1(const int* __restrict__ deg,
                                               int* __restrict__ loc,
                                               int* __restrict__ bsum, int n) {
    __shared__ int sh[256];
    int tid = threadIdx.x;
    int base = blockIdx.x * 1024 + tid * 4;
    int v[4];
#pragma unroll
    for (int j = 0; j < 4; j++) v[j] = (base + j < n) ? deg[base + j] : 0;
    int tsum = v[0] + v[1] + v[2] + v[3];
    int val = tsum;
    sh[tid] = val;
    __syncthreads();
    for (int off = 1; off < 256; off <<= 1) {
        int o = (tid >= off) ? sh[tid - off] : 0;
        __syncthreads();
        val += o;
        sh[tid] = val;
        __syncthreads();
    }
    if (tid == 255) bsum[blockIdx.x] = val;
    int run = val - tsum;  // exclusive over thread sums
#pragma unroll
    for (int j = 0; j < 4; j++) {
        if (base + j < n) loc[base + j] = run;
        run += v[j];
    }
}

// single block: exclusive scan of nb block sums (nb <= 256)
__global__ __launch_bounds__(256) void k_scan2(int* __restrict__ bsum, int nb) {
    __shared__ int sh[256];
    int tid = threadIdx.x;
    int orig = (tid < nb) ? bsum[tid] : 0;
    int val = orig;
    sh[tid] = val;
    __syncthreads();
    for (int off = 1; off < 256; off <<= 1) {
        int o = (tid >= off) ? sh[tid - off] : 0;
        __syncthreads();
        val += o;
        sh[tid] = val;
        __syncthreads();
    }
    if (tid < nb) bsum[tid] = val - orig;      // exclusive
    if (tid == nb - 1) bsum[nb] = val;         // total = E + N
}

__global__ void k_scan3(const int* __restrict__ deg, int* __restrict__ offs,
                        const int* __restrict__ bsum, int* __restrict__ cursor,
                        float* __restrict__ dinv, int n, int nb) {
    int i = blockIdx.x * blockDim.x + threadIdx.x;
    if (i < n) {
        int off = offs[i] + bsum[i >> 10];
        offs[i] = off;
        cursor[i] = off;
        dinv[i] = rsqrtf((float)deg[i]);
    }
    if (i == 0) offs[n] = bsum[nb];
}

__global__ void k_fill(const int* __restrict__ esrc, const int* __restrict__ edst,
                       const float* __restrict__ dinv, int* __restrict__ cursor,
                       int2* __restrict__ epk, int E, int n) {
    int e = blockIdx.x * blockDim.x + threadIdx.x;
    if (e < E) {
        int s = esrc[e], d = edst[e];
        int pos = atomicAdd(&cursor[d], 1);
        float w = dinv[s] * dinv[d];
        epk[pos] = int2{s, __float_as_int(w)};
    } else if (e < E + n) {
        int i = e - E;
        int pos = atomicAdd(&cursor[i], 1);
        float di = dinv[i];
        epk[pos] = int2{i, __float_as_int(di * di)};
    }
}

// T[N,F] = H[N,128] @ W[128,F]. W staged in LDS (F*512 B), 128 rows/block,
// 1024 threads, each thread: RPT rows x 1 float4 col. 2 blocks/CU target.
template <int F>
__global__ __launch_bounds__(1024, 8) void k_gemm(const float* __restrict__ H,
                                                  const float* __restrict__ W,
                                                  float* __restrict__ T, int n) {
    constexpr int TX = F / 4;          // 32 (F=128) or 16 (F=64)
    constexpr int TY = 1024 / TX;      // 32 or 64
    constexpr int RPT = 128 / TY;      // 4 or 2
    __shared__ float Wl[128 * F];
    int tid = threadIdx.x;
#pragma unroll
    for (int i = 0; i < (128 * F) / 4096; i++)
        *(float4*)&Wl[tid * 4 + i * 4096] = *(const float4*)&W[tid * 4 + i * 4096];
    __syncthreads();
    int tx = tid % TX, ty = tid / TX;
    int row0 = blockIdx.x * 128 + ty * RPT;
    // clamp OOB rows (values unused; stores are guarded) -> unconditional loads
    const float* hp[RPT];
#pragma unroll
    for (int i = 0; i < RPT; i++) hp[i] = H + (size_t)min(row0 + i, n - 1) * 128;
    float4 acc[RPT];
#pragma unroll
    for (int i = 0; i < RPT; i++) acc[i] = float4{0.f, 0.f, 0.f, 0.f};
#pragma unroll 2
    for (int k4 = 0; k4 < 32; k4++) {
        float4 xq[RPT];
#pragma unroll
        for (int i = 0; i < RPT; i++) xq[i] = *(const float4*)(hp[i] + k4 * 4);
#pragma unroll
        for (int kk = 0; kk < 4; kk++) {
            float4 wv = *(const float4*)&Wl[(k4 * 4 + kk) * F + tx * 4];
#pragma unroll
            for (int i = 0; i < RPT; i++) {
                float xs = (&xq[i].x)[kk];
                acc[i].x += xs * wv.x;
                acc[i].y += xs * wv.y;
                acc[i].z += xs * wv.z;
                acc[i].w += xs * wv.w;
            }
        }
    }
#pragma unroll
    for (int i = 0; i < RPT; i++) {
        int r = row0 + i;
        if (r < n) *(float4*)&T[(size_t)r * F + tx * 4] = acc[i];
    }
}

// one wave per dst node. F=128: two 32-lane halves, each gathers a full 512B
// row as float4/lane; 2 edges per step. F=64: four 16-lane quarters, 4 edges
// per step. Edge {src,w} preloaded 64-wide, broadcast via shfl. fp64 acc.
template <int F, bool RELU>
__global__ __launch_bounds__(256) void k_prop(const float* __restrict__ T,
                                              const int* __restrict__ offs,
                                              const int2* __restrict__ epk,
                                              const float* __restrict__ bias,
                                              float* __restrict__ Out, int n) {
    constexpr int GRP = F / 4;          // lanes per edge-group: 32 or 16
    constexpr int EPS = 64 / GRP;       // edges per step: 2 or 4
    int wid = (blockIdx.x * blockDim.x + threadIdx.x) >> 6;  // node id
    int lane = threadIdx.x & 63;
    if (wid >= n) return;
    int gh = lane / GRP;                // which edge within a step
    int fl = lane % GRP;                // feature lane within group
    int beg = offs[wid], end = offs[wid + 1];
    double a0 = 0.0, a1 = 0.0, a2 = 0.0, a3 = 0.0;
    for (int base = beg; base < end; base += 64) {
        int cnt = min(64, end - base);
        int sv = 0;
        float wv = 0.f;
        if (lane < cnt) {
            int2 ev = epk[base + lane];
            sv = ev.x;
            wv = __int_as_float(ev.y);
        }
        for (int j = 0; j < cnt; j += EPS) {
            int e = j + gh;             // e <= 63 always (see note below)
            int s = __shfl(sv, e);
            float w = __shfl(wv, e);    // lanes >= cnt preloaded w=0
            float4 v = *(const float4*)&T[(size_t)s * F + fl * 4];
            a0 += (double)(w * v.x);
            a1 += (double)(w * v.y);
            a2 += (double)(w * v.z);
            a3 += (double)(w * v.w);
        }
        // note: j <= 4*ceil(cnt/EPS)-EPS <= 60 (EPS=4) or 62 (EPS=2, cnt<=64),
        // so e = j+gh <= 63; any e >= cnt hits a zero-weight preload lane.
    }
    // reduce across edge-groups (halves / quarters hold partial sums)
#pragma unroll
    for (int m = 32; m >= GRP; m >>= 1) {
        a0 += __shfl_xor(a0, m);
        a1 += __shfl_xor(a1, m);
        a2 += __shfl_xor(a2, m);
        a3 += __shfl_xor(a3, m);
    }
    if (gh == 0) {
        float4 b = *(const float4*)&bias[fl * 4];
        float r0 = (float)a0 + b.x;
        float r1 = (float)a1 + b.y;
        float r2 = (float)a2 + b.z;
        float r3 = (float)a3 + b.w;
        if (RELU) {
            r0 = fmaxf(r0, 0.f); r1 = fmaxf(r1, 0.f);
            r2 = fmaxf(r2, 0.f); r3 = fmaxf(r3, 0.f);
        }
        *(float4*)&Out[(size_t)wid * F + fl * 4] = float4{r0, r1, r2, r3};
    }
}

extern "C" void kernel_launch(void* const* d_in, const int* in_sizes, int n_in,
                              void* d_out, int out_size, void* d_ws, size_t ws_size,
                              hipStream_t stream) {
    const float* x  = (const float*)d_in[0];
    const int*   ei = (const int*)d_in[1];
    const float* W1 = (const float*)d_in[2];
    const float* b1 = (const float*)d_in[3];
    const float* W2 = (const float*)d_in[4];
    const float* b2 = (const float*)d_in[5];
    const float* W3 = (const float*)d_in[6];
    const float* b3 = (const float*)d_in[7];
    float* out = (float*)d_out;

    const int HID = in_sizes[3];            // 128
    const int IN  = in_sizes[2] / HID;      // 128
    const int N   = in_sizes[0] / IN;       // 100000
    const int E   = in_sizes[1] / 2;        // 1600000
    const int nb  = (N + 1023) / 1024;      // scan blocks

    const int* esrc = ei;
    const int* edst = ei + E;

    // workspace carve-up (256B aligned)
    char* p = (char*)d_ws;
    auto alloc = [&](size_t bytes) {
        void* r = (void*)p;
        p += (bytes + 255) & ~(size_t)255;
        return r;
    };
    int*   deg    = (int*)alloc((size_t)N * 4);
    float* dinv   = (float*)alloc((size_t)N * 4);
    int*   offs   = (int*)alloc((size_t)(N + 1) * 4);
    int*   bsum   = (int*)alloc((size_t)(nb + 2) * 4);
    int*   cursor = (int*)alloc((size_t)N * 4);
    int2*  epk    = (int2*)alloc((size_t)(E + N) * 8);
    float* t0     = (float*)alloc((size_t)N * 128 * 4);
    float* h0     = (float*)alloc((size_t)N * 128 * 4);
    (void)ws_size; (void)n_in; (void)out_size;

    const int B = 256;
    // --- graph norm + CSR build (once; reused by all 3 layers) ---
    k_init_deg<<<(N + B - 1) / B, B, 0, stream>>>(deg, N);
    k_hist<<<(E + B - 1) / B, B, 0, stream>>>(edst, deg, E);
    k_scan1<<<nb, B, 0, stream>>>(deg, offs, bsum, N);
    k_scan2<<<1, B, 0, stream>>>(bsum, nb);
    k_scan3<<<(N + B - 1) / B, B, 0, stream>>>(deg, offs, bsum, cursor, dinv, N, nb);
    k_fill<<<(E + N + B - 1) / B, B, 0, stream>>>(esrc, edst, dinv, cursor, epk, E, N);

    const int gb = (N + 127) / 128;  // gemm row-blocks
    const int pb = (N * 64 + B - 1) / B;
    // --- layer 1 ---
    k_gemm<128><<<gb, 1024, 0, stream>>>(x, W1, t0, N);
    k_prop<128, true><<<pb, B, 0, stream>>>(t0, offs, epk, b1, h0, N);
    // --- layer 2 ---
    k_gemm<128><<<gb, 1024, 0, stream>>>(h0, W2, t0, N);
    k_prop<128, true><<<pb, B, 0, stream>>>(t0, offs, epk, b2, h0, N);
    // --- layer 3 (OUT=64, no relu, into d_out) ---
    k_gemm<64><<<gb, 1024, 0, stream>>>(h0, W3, t0, N);
    k_prop<64, false><<<pb, B, 0, stream>>>(t0, offs, epk, b3, out, N);
}